// Round 10
// baseline (391.484 us; speedup 1.0000x reference)
//
#include <hip/hip_runtime.h>
#include <hip/hip_bf16.h>
#include <cstdint>

#define BATCH  4
#define SEQ    2048
#define DMODEL 1024
#define DFF    4096
#define MTOT   (BATCH * SEQ)   // 8192
#define KCONV  5
#define PADC   2

using bf16raw = unsigned short;
typedef __attribute__((ext_vector_type(8))) short bf16x8;
typedef __attribute__((ext_vector_type(4))) float f32x4;

__device__ __forceinline__ float bf2f(bf16raw u) {
    return __uint_as_float(((uint32_t)u) << 16);
}
__device__ __forceinline__ bf16raw f2bf(float f) {
    uint32_t u = __float_as_uint(f);
    u = (u + 0x7fffu + ((u >> 16) & 1u)) >> 16;   // RNE
    return (bf16raw)u;
}

// ---------------- prep kernels ----------------

__global__ __launch_bounds__(256)
void cvt_bf16_kernel(const float* __restrict__ in, bf16raw* __restrict__ out, int n4)
{
    const int i = blockIdx.x * 256 + threadIdx.x;
    if (i >= n4) return;
    const float4 v = reinterpret_cast<const float4*>(in)[i];
    ushort4 o;
    o.x = f2bf(v.x); o.y = f2bf(v.y); o.z = f2bf(v.z); o.w = f2bf(v.w);
    reinterpret_cast<ushort4*>(out)[i] = o;
}

// out[C][R] = bf16(in[R][C]); R,C multiples of 32
__global__ __launch_bounds__(256)
void transpose_cvt_kernel(const float* __restrict__ in, bf16raw* __restrict__ out,
                          int R, int C)
{
    __shared__ float tile[32][33];
    const int r0 = blockIdx.y * 32, c0 = blockIdx.x * 32;
    const int tx = threadIdx.x & 31, ty = threadIdx.x >> 5;  // ty 0..7
#pragma unroll
    for (int i = 0; i < 4; ++i)
        tile[ty + i * 8][tx] = in[(size_t)(r0 + ty + i * 8) * C + c0 + tx];
    __syncthreads();
#pragma unroll
    for (int i = 0; i < 4; ++i)
        out[(size_t)(c0 + ty + i * 8) * R + r0 + tx] = f2bf(tile[tx][ty + i * 8]);
}

// conv weights [DFF][1][K] -> [K][DFF] fp32
__global__ __launch_bounds__(256)
void convw_reorder_kernel(const float* __restrict__ wg, const float* __restrict__ wu,
                          float* __restrict__ wgT, float* __restrict__ wuT)
{
    const int i = blockIdx.x * 256 + threadIdx.x;
    if (i >= KCONV * DFF) return;
    const int j = i / DFF, f = i - j * DFF;
    wgT[i] = wg[f * KCONV + j];
    wuT[i] = wu[f * KCONV + j];
}

// -- 256x256 GEMM, BK=32, 4-buf ring, 4-phase READ-AHEAD pipeline (r10) --------
// C[M][N] = A[M][K] @ BT[N][K]^T (+bias); M,N %256==0, K%(32*SPLITK)==0, NT>=4.
// r10 theory: r4..r9 all additive (T = T_dsread + T_mfma per tile) because each
// MFMA burst's reads immediately precede it (true dep -> no overlap) and MFMA
// issue backpressure delays the next reads. Fix: phase s issues set s+1's reads
// (into the ALTERNATE reg set), then runs set s's 8 MFMA -> reads execute in
// the LDS pipe while the matrix pipe drains. Sets: set s = A-frags mf{2s,2s+1};
// B-frags (4) read once per tile at s=3 of the previous tile (Bc/Bn swap via
// even/odd unrolled bodies -> no runtime-indexed register arrays, rule #20).
// Stage distance 3 on a 4-buf ring; vmcnt(4) per tile (never 0 mid-loop):
// at tile t's sync, outstanding = tiles {t+1 (issued at t-2), t+2 (at t-1)} = 8
// loads; vmcnt(4) drains exactly t+1 (needed by s=3's set0(t+1) reads). WAR:
// stage(t+3) targets buf[(t-1)&3], last read at s2 of tile t-1, >=1 barrier ago.
// Swizzle (r6/r9-proven, 0 conflicts): 64B rows, phys16B = log ^ ((row>>1)&3).

__device__ __forceinline__ void gll16(const bf16raw* g, const char* lds)
{
    __builtin_amdgcn_global_load_lds(
        (const __attribute__((address_space(1))) void*)g,
        (__attribute__((address_space(3))) void*)lds, 16, 0, 0);
}

template<typename CT, bool BIAS, int SPLITK, bool COLMAJOR>
__global__ __launch_bounds__(512, 2)
void gemmp_kernel(const bf16raw* __restrict__ A, const bf16raw* __restrict__ BT,
                  const float* __restrict__ bias0, const float* __restrict__ bias1,
                  CT* __restrict__ C, int M, int N, int K, int nbm, int nbn)
{
    __shared__ __align__(16) char smem[131072];   // 4 bufs x (A 16K | B 16K)

    const int tid  = threadIdx.x;
    const int lane = tid & 63;
    const int wave = __builtin_amdgcn_readfirstlane(tid >> 6);
    const int wr = wave >> 2;          // 0..1 (M)
    const int wc = wave & 3;           // 0..3 (N)

    // XCD-aware swizzle (grid multiple of 8)
    const int nwg = nbm * nbn * SPLITK;
    const int cpx = nwg >> 3;
    const int bid = blockIdx.x;
    const int swz = (bid & 7) * cpx + (bid >> 3);
    int sk = 0, rem = swz;
    if constexpr (SPLITK > 1) { sk = swz / (nbm * nbn); rem = swz - sk * (nbm * nbn); }
    int bx, by;
    if constexpr (COLMAJOR) { bx = rem / nbm; by = rem - bx * nbm; }   // B-stationary
    else                    { by = rem / nbn; bx = rem - by * nbn; }   // A-stationary
    const int bm = by * 256;
    const int bn = bx * 256;

    const int klen = K / SPLITK;
    const int kbeg = sk * klen;
    const int NT   = klen / 32;
    CT* Cp = C + (size_t)sk * M * N;

    // staging: thread -> row = half*128 + tid>>2, phys 16B chunk = tid&3.
    // LDS dest linear in lane: (l>>2)*64 + (l&3)*16 == 16*l  (gll-safe).
    const int srow  = tid >> 2;               // 0..127
    const int sphys = tid & 3;

    auto stage = [&](int t) {
#pragma unroll
        for (int half = 0; half < 2; ++half) {
            const int row = half * 128 + srow;
            gll16(A + (size_t)(bm + row) * K + kbeg + t * 32
                    + ((sphys ^ ((row >> 1) & 3)) << 3),
                  smem + (size_t)(t & 3) * 32768 + row * 64 + sphys * 16);
        }
#pragma unroll
        for (int half = 0; half < 2; ++half) {
            const int row = half * 128 + srow;
            gll16(BT + (size_t)(bn + row) * K + kbeg + t * 32
                    + ((sphys ^ ((row >> 1) & 3)) << 3),
                  smem + (size_t)(t & 3) * 32768 + 16384 + row * 64 + sphys * 16);
        }
    };

    // fragment reads: row = base + r15; swizzle key depends only on (r15>>1)&3
    const int g4   = lane >> 4;
    const int r15  = lane & 15;
    const int koff = ((g4 ^ ((r15 >> 1) & 3)) << 4);

    auto ldA = [&](int buf, int mf) -> bf16x8 {
        return *(const bf16x8*)(smem + (size_t)buf * 32768
                                + (wr * 128 + mf * 16 + r15) * 64 + koff);
    };
    auto ldB = [&](int buf, int nf) -> bf16x8 {
        return *(const bf16x8*)(smem + (size_t)buf * 32768 + 16384
                                + (wc * 64 + nf * 16 + r15) * 64 + koff);
    };

    f32x4 acc[8][4];
#pragma unroll
    for (int i = 0; i < 8; ++i)
#pragma unroll
        for (int j = 0; j < 4; ++j) acc[i][j] = (f32x4){0.f, 0.f, 0.f, 0.f};

    bf16x8 A0[2], A1[2], Bb0[4], Bb1[4];

#define MFMA_SET(M0, ASET, BSET)                                               \
    __builtin_amdgcn_s_setprio(1);                                             \
    _Pragma("unroll")                                                          \
    for (int i_ = 0; i_ < 2; ++i_)                                             \
        _Pragma("unroll")                                                      \
        for (int nf_ = 0; nf_ < 4; ++nf_)                                      \
            acc[(M0) + i_][nf_] = __builtin_amdgcn_mfma_f32_16x16x32_bf16(     \
                ASET[i_], BSET[nf_], acc[(M0) + i_][nf_], 0, 0, 0);            \
    __builtin_amdgcn_s_setprio(0);

#define TILE_BODY(T, BC, BN)                                                   \
    {                                                                          \
        const int t_   = (T);                                                  \
        const int buf_ = t_ & 3;                                               \
        /* s0: read set1 -> A1; MFMA set0 (A0 x BC) */                         \
        A1[0] = ldA(buf_, 2); A1[1] = ldA(buf_, 3);                            \
        MFMA_SET(0, A0, BC)                                                    \
        /* s1: read set2 -> A0; MFMA set1 (A1 x BC) */                         \
        A0[0] = ldA(buf_, 4); A0[1] = ldA(buf_, 5);                            \
        MFMA_SET(2, A1, BC)                                                    \
        /* s2: read set3 -> A1; MFMA set2 (A0 x BC) */                         \
        A1[0] = ldA(buf_, 6); A1[1] = ldA(buf_, 7);                            \
        MFMA_SET(4, A0, BC)                                                    \
        /* sync: drain tile t+1's 4 loads, keep t+2's in flight */             \
        if (t_ + 2 < NT) asm volatile("s_waitcnt vmcnt(4)" ::: "memory");      \
        else             asm volatile("s_waitcnt vmcnt(0)" ::: "memory");      \
        __builtin_amdgcn_s_barrier();                                          \
        asm volatile("" ::: "memory");                                         \
        if (t_ + 3 < NT) stage(t_ + 3);                                        \
        /* s3: read set0(t+1) -> BN + A0; MFMA set3 (A1 x BC) */               \
        if (t_ + 1 < NT) {                                                     \
            const int nb_ = (t_ + 1) & 3;                                      \
            BN[0] = ldB(nb_, 0); BN[1] = ldB(nb_, 1);                          \
            BN[2] = ldB(nb_, 2); BN[3] = ldB(nb_, 3);                          \
            A0[0] = ldA(nb_, 0); A0[1] = ldA(nb_, 1);                          \
        }                                                                      \
        MFMA_SET(6, A1, BC)                                                    \
        asm volatile("" ::: "memory");                                         \
    }

    // prologue: stage tiles 0..2, wait tile0, read set0(0)
    stage(0);
    if (NT > 1) stage(1);
    if (NT > 2) stage(2);
    if (NT > 2)      asm volatile("s_waitcnt vmcnt(8)" ::: "memory");
    else if (NT > 1) asm volatile("s_waitcnt vmcnt(4)" ::: "memory");
    else             asm volatile("s_waitcnt vmcnt(0)" ::: "memory");
    __builtin_amdgcn_s_barrier();
    asm volatile("" ::: "memory");
    Bb0[0] = ldB(0, 0); Bb0[1] = ldB(0, 1); Bb0[2] = ldB(0, 2); Bb0[3] = ldB(0, 3);
    A0[0]  = ldA(0, 0); A0[1]  = ldA(0, 1);

    for (int tt = 0; tt < NT; tt += 2) {
        TILE_BODY(tt, Bb0, Bb1)
        if (tt + 1 < NT) TILE_BODY(tt + 1, Bb1, Bb0)
    }
#undef TILE_BODY
#undef MFMA_SET

    // ---- epilogue: C/D layout col=lane&15, row=(lane>>4)*4+reg  [m89] ----
    const int er = g4 << 2;
#pragma unroll
    for (int nf = 0; nf < 4; ++nf) {
        const int nn = bn + wc * 64 + nf * 16 + r15;
        float bv = 0.f;
        if constexpr (BIAS) bv = (nn < DFF) ? bias0[nn] : bias1[nn - DFF];
#pragma unroll
        for (int mf = 0; mf < 8; ++mf) {
            const int mrow = bm + wr * 128 + mf * 16 + er;
#pragma unroll
            for (int j = 0; j < 4; ++j) {
                const float v = acc[mf][nf][j] + bv;
                if constexpr (sizeof(CT) == 2)
                    Cp[(size_t)(mrow + j) * N + nn] = f2bf(v);
                else
                    Cp[(size_t)(mrow + j) * N + nn] = v;
            }
        }
    }
}

// ---------------- split-K reduce + bias (fp32 partials -> fp32 out) --------
template<int NS>
__global__ __launch_bounds__(256)
void reduce_bias_kernel(const float* __restrict__ part, const float* __restrict__ bd,
                        float* __restrict__ out)
{
    const int i = blockIdx.x * 256 + threadIdx.x;           // float4 index
    const int d = (i & (DMODEL / 4 - 1)) * 4;
    const float4 bb = *reinterpret_cast<const float4*>(bd + d);
    float4 o; o.x = bb.x; o.y = bb.y; o.z = bb.z; o.w = bb.w;
#pragma unroll
    for (int s = 0; s < NS; ++s) {
        const float4 a = reinterpret_cast<const float4*>(part + (size_t)s * MTOT * DMODEL)[i];
        o.x += a.x; o.y += a.y; o.z += a.z; o.w += a.w;
    }
    reinterpret_cast<float4*>(out)[i] = o;
}

// ---------------- conv + silu + mul (bf16 in/out, src row stride S) --------
__global__ __launch_bounds__(256)
void conv_silu_mul_bf16_kernel(const bf16raw* __restrict__ gp, const bf16raw* __restrict__ up,
                               const float* __restrict__ wgT, const float* __restrict__ cbg,
                               const float* __restrict__ wuT, const float* __restrict__ cbu,
                               bf16raw* __restrict__ h, int S)
{
    const int idx = blockIdx.x * 256 + threadIdx.x;
    const int f   = (idx & (DFF / 8 - 1)) << 3;
    const int row = idx >> 9;
    const int l   = row & (SEQ - 1);
    const int rb  = row - l;                       // batch base row

    float g[8], u[8];
    {
        const float4 a0 = *reinterpret_cast<const float4*>(cbg + f);
        const float4 a1 = *reinterpret_cast<const float4*>(cbg + f + 4);
        const float4 b0 = *reinterpret_cast<const float4*>(cbu + f);
        const float4 b1 = *reinterpret_cast<const float4*>(cbu + f + 4);
        g[0]=a0.x; g[1]=a0.y; g[2]=a0.z; g[3]=a0.w; g[4]=a1.x; g[5]=a1.y; g[6]=a1.z; g[7]=a1.w;
        u[0]=b0.x; u[1]=b0.y; u[2]=b0.z; u[3]=b0.w; u[4]=b1.x; u[5]=b1.y; u[6]=b1.z; u[7]=b1.w;
    }

#pragma unroll
    for (int j = 0; j < KCONV; ++j) {
        const int ls = l + j - PADC;
        if (ls < 0 || ls >= SEQ) continue;          // per-batch zero padding
        const size_t off = (size_t)(rb + ls) * S + f;
        const bf16x8 gv = *reinterpret_cast<const bf16x8*>(gp + off);
        const bf16x8 uv = *reinterpret_cast<const bf16x8*>(up + off);
        const float4 wa0 = *reinterpret_cast<const float4*>(wgT + j * DFF + f);
        const float4 wa1 = *reinterpret_cast<const float4*>(wgT + j * DFF + f + 4);
        const float4 wb0 = *reinterpret_cast<const float4*>(wuT + j * DFF + f);
        const float4 wb1 = *reinterpret_cast<const float4*>(wuT + j * DFF + f + 4);
        const float wg8[8] = {wa0.x, wa0.y, wa0.z, wa0.w, wa1.x, wa1.y, wa1.z, wa1.w};
        const float wu8[8] = {wb0.x, wb0.y, wb0.z, wb0.w, wb1.x, wb1.y, wb1.z, wb1.w};
#pragma unroll
        for (int c = 0; c < 8; ++c) {
            g[c] += bf2f((bf16raw)gv[c]) * wg8[c];
            u[c] += bf2f((bf16raw)uv[c]) * wu8[c];
        }
    }

    bf16x8 hv;
#pragma unroll
    for (int c = 0; c < 8; ++c) {
        const float s = g[c] / (1.f + __expf(-g[c]));
        hv[c] = (short)f2bf(s * u[c]);
    }
    *reinterpret_cast<bf16x8*>(h + (size_t)row * DFF + f) = hv;
}

// ---------------- fp32 fallback kernels (round-2 proven) -------------------

#define BM 128
#define BN 128
#define BK 8

__device__ __forceinline__ void load4f(const float* p, float v[4]) {
    const float4 t = *reinterpret_cast<const float4*>(p);
    v[0] = t.x; v[1] = t.y; v[2] = t.z; v[3] = t.w;
}

__global__ __launch_bounds__(256)
void sgemm_bias_kernel(const float* __restrict__ A, const float* __restrict__ B,
                       const float* __restrict__ bias, float* __restrict__ C,
                       int N, int K)
{
    __shared__ float As[BK][BM];
    __shared__ float Bs[BK][BN];

    const int tid = threadIdx.x;
    const int bm  = blockIdx.y * BM;
    const int bn  = blockIdx.x * BN;
    const int tx  = tid & 15;
    const int ty  = tid >> 4;

    const int arow = tid >> 1;
    const int acol = (tid & 1) * 4;
    const int brow = tid >> 5;
    const int bcol = (tid & 31) * 4;

    const float* Ap = A + (size_t)(bm + arow) * K + acol;
    const float* Bp = B + (size_t)brow * N + bn + bcol;

    float acc[8][8];
#pragma unroll
    for (int i = 0; i < 8; ++i)
#pragma unroll
        for (int j = 0; j < 8; ++j) acc[i][j] = 0.f;

    for (int k0 = 0; k0 < K; k0 += BK) {
        float av[4];
        load4f(Ap + k0, av);
        const float4 bv = *reinterpret_cast<const float4*>(Bp + (size_t)k0 * N);
        __syncthreads();
#pragma unroll
        for (int i = 0; i < 4; ++i) As[acol + i][arow] = av[i];
        *reinterpret_cast<float4*>(&Bs[brow][bcol]) = bv;
        __syncthreads();
#pragma unroll
        for (int kk = 0; kk < BK; ++kk) {
            const float4 a0 = *reinterpret_cast<const float4*>(&As[kk][ty * 4]);
            const float4 a1 = *reinterpret_cast<const float4*>(&As[kk][64 + ty * 4]);
            const float4 b0 = *reinterpret_cast<const float4*>(&Bs[kk][tx * 4]);
            const float4 b1 = *reinterpret_cast<const float4*>(&Bs[kk][64 + tx * 4]);
            const float am[8] = {a0.x, a0.y, a0.z, a0.w, a1.x, a1.y, a1.z, a1.w};
            const float bb[8] = {b0.x, b0.y, b0.z, b0.w, b1.x, b1.y, b1.z, b1.w};
#pragma unroll
            for (int mi = 0; mi < 8; ++mi)
#pragma unroll
                for (int nj = 0; nj < 8; ++nj)
                    acc[mi][nj] += am[mi] * bb[nj];
        }
    }
#pragma unroll
    for (int mi = 0; mi < 8; ++mi) {
        const int m = bm + ((mi < 4) ? (ty * 4 + mi) : (64 + ty * 4 + (mi - 4)));
#pragma unroll
        for (int g = 0; g < 2; ++g) {
            const int n = bn + g * 64 + tx * 4;
            float4 o;
            o.x = acc[mi][g * 4 + 0] + bias[n + 0];
            o.y = acc[mi][g * 4 + 1] + bias[n + 1];
            o.z = acc[mi][g * 4 + 2] + bias[n + 2];
            o.w = acc[mi][g * 4 + 3] + bias[n + 3];
            *reinterpret_cast<float4*>(&C[(size_t)m * N + n]) = o;
        }
    }
}

__global__ __launch_bounds__(256)
void conv_silu_mul_f32_kernel(const float* __restrict__ gp, const float* __restrict__ up,
                              const float* __restrict__ wg, const float* __restrict__ cbg,
                              const float* __restrict__ wu, const float* __restrict__ cbu,
                              float* __restrict__ hout)
{
    const int idx = blockIdx.x * 256 + threadIdx.x;
    const int f   = (idx & (DFF / 4 - 1)) * 4;
    const int l   = idx >> 10;

    float g[4], u[4];
    load4f(cbg + f, g);
    load4f(cbu + f, u);
#pragma unroll
    for (int j = 0; j < KCONV; ++j) {
        const int ls = l + j - PADC;
        if (ls < 0 || ls >= SEQ) continue;
        const size_t off = (size_t)ls * DFF + f;
        float gv[4], uv[4];
        load4f(gp + off, gv);
        load4f(up + off, uv);
#pragma unroll
        for (int c = 0; c < 4; ++c) {
            g[c] += gv[c] * wg[(f + c) * KCONV + j];
            u[c] += uv[c] * wu[(f + c) * KCONV + j];
        }
    }
    float h[4];
#pragma unroll
    for (int c = 0; c < 4; ++c) {
        const float s = g[c] / (1.f + __expf(-g[c]));
        h[c] = s * u[c];
    }
    float4 o; o.x = h[0]; o.y = h[1]; o.z = h[2]; o.w = h[3];
    *reinterpret_cast<float4*>(&hout[(size_t)l * DFF + f]) = o;
}

// ---------------- launch ----------------

extern "C" void kernel_launch(void* const* d_in, const int* in_sizes, int n_in,
                              void* d_out, int out_size, void* d_ws, size_t ws_size,
                              hipStream_t stream)
{
    const float* x   = (const float*)d_in[0];
    const float* Wg  = (const float*)d_in[1];
    const float* bg  = (const float*)d_in[2];
    const float* Wu  = (const float*)d_in[3];
    const float* bu  = (const float*)d_in[4];
    const float* cgw = (const float*)d_in[5];
    const float* cgb = (const float*)d_in[6];
    const float* cuw = (const float*)d_in[7];
    const float* cub = (const float*)d_in[8];
    const float* Wd  = (const float*)d_in[9];
    const float* bd  = (const float*)d_in[10];
    float* out = (float*)d_out;

    const dim3 blk(256);
    auto align256 = [](size_t v) { return (v + 255) & ~(size_t)255; };

    const size_t SZ_XB  = (size_t)MTOT * DMODEL * 2;        // 16 MiB
    const size_t SZ_WGU = (size_t)2 * DFF * DMODEL * 2;     // 16 MiB (Wg^T | Wu^T)
    const size_t SZ_WD  = (size_t)DMODEL * DFF * 2;         //  8 MiB
    const size_t SZ_CW  = (size_t)KCONV * DFF * 4;          // 80 KiB each
    const size_t SZ_H   = (size_t)MTOT * DFF * 2;           // 64 MiB
    const size_t SZ_UP  = (size_t)MTOT * 2 * DFF * 2;       // 128 MiB  [8192][8192] bf16

    size_t cur = 0;
    const size_t oXB  = cur; cur = align256(cur + SZ_XB);
    const size_t oWGU = cur; cur = align256(cur + SZ_WGU);
    const size_t oWD  = cur; cur = align256(cur + SZ_WD);
    const size_t oCWg = cur; cur = align256(cur + SZ_CW);
    const size_t oCWu = cur; cur = align256(cur + SZ_CW);
    const size_t oH   = cur; cur = align256(cur + SZ_H);
    const size_t oUP  = cur; cur = align256(cur + SZ_UP);
    const size_t need = cur;

    if (ws_size >= need) {
        bf16raw* xb   = (bf16raw*)((char*)d_ws + oXB);
        bf16raw* Wgu  = (bf16raw*)((char*)d_ws + oWGU);
        bf16raw* WdT  = (bf16raw*)((char*)d_ws + oWD);
        float*   cwg  = (float*)((char*)d_ws + oCWg);
        float*   cwu  = (float*)((char*)d_ws + oCWu);
        bf16raw* h    = (bf16raw*)((char*)d_ws + oH);
        bf16raw* Cup  = (bf16raw*)((char*)d_ws + oUP);
        float*   part = (float*)((char*)d_ws + oUP);        // overlay (conv consumed Cup)

        cvt_bf16_kernel<<<(MTOT * DMODEL / 4 + 255) / 256, blk, 0, stream>>>(x, xb, MTOT * DMODEL / 4);
        transpose_cvt_kernel<<<dim3(DFF / 32, DMODEL / 32), blk, 0, stream>>>(Wg, Wgu, DMODEL, DFF);
        transpose_cvt_kernel<<<dim3(DFF / 32, DMODEL / 32), blk, 0, stream>>>(Wu, Wgu + (size_t)DFF * DMODEL, DMODEL, DFF);
        transpose_cvt_kernel<<<dim3(DMODEL / 32, DFF / 32), blk, 0, stream>>>(Wd, WdT, DFF, DMODEL);
        convw_reorder_kernel<<<(KCONV * DFF + 255) / 256, blk, 0, stream>>>(cgw, cuw, cwg, cwu);

        // fused up-GEMM: [8192,1024] @ [1024,8192(=Wg|Wu)] -> Cup [8192][8192] bf16
        {
            const int nbm = MTOT / 256, nbn = (2 * DFF) / 256;   // 32 x 32 -> 1024 wg
            gemmp_kernel<bf16raw, true, 1, true><<<nbm * nbn, dim3(512), 0, stream>>>(
                xb, Wgu, bg, bu, Cup, MTOT, 2 * DFF, DMODEL, nbm, nbn);
        }

        // conv + silu + mul: Cup(gate 0..4095 | up 4096..8191) -> h bf16
        conv_silu_mul_bf16_kernel<<<MTOT * (DFF / 8) / 256, blk, 0, stream>>>(
            Cup, Cup + DFF, cwg, cgb, cwu, cub, h, 2 * DFF);

        // down-GEMM split-K=2 (A/h-stationary XCD chunks) -> fp32 partials
        {
            const int nbm = MTOT / 256, nbn = DMODEL / 256;      // 32 x 4, x2 sk
            gemmp_kernel<float, false, 2, false><<<nbm * nbn * 2, dim3(512), 0, stream>>>(
                h, WdT, nullptr, nullptr, part, MTOT, DMODEL, DFF, nbm, nbn);
        }
        reduce_bias_kernel<2><<<MTOT * DMODEL / 4 / 256, blk, 0, stream>>>(part, bd, out);
        return;
    }

    // -------- fp32 per-batch fallback --------
    const size_t CE  = (size_t)SEQ * DFF;
    const size_t P32 = CE * sizeof(float);
    if (ws_size < 3 * P32) return;

    float* gpre = (float*)d_ws;
    float* upre = gpre + CE;
    float* hbuf = upre + CE;
    dim3 gu(DFF / BN, SEQ / BM);
    dim3 gdc(DMODEL / BN, SEQ / BM);
    const int nconv = SEQ * (DFF / 4) / 256;
    for (int b = 0; b < BATCH; ++b) {
        const float* xbp = x + (size_t)b * SEQ * DMODEL;
        float* outb = out + (size_t)b * SEQ * DMODEL;
        sgemm_bias_kernel<<<gu, blk, 0, stream>>>(xbp, Wg, bg, gpre, DFF, DMODEL);
        sgemm_bias_kernel<<<gu, blk, 0, stream>>>(xbp, Wu, bu, upre, DFF, DMODEL);
        conv_silu_mul_f32_kernel<<<nconv, blk, 0, stream>>>(gpre, upre, cgw, cgb, cuw, cub, hbuf);
        sgemm_bias_kernel<<<gdc, blk, 0, stream>>>(hbuf, Wd, bd, outb, DMODEL, DFF);
    }
}

// Round 11
// 387.698 us; speedup vs baseline: 1.0098x; 1.0098x over previous
//
#include <hip/hip_runtime.h>
#include <hip/hip_bf16.h>
#include <cstdint>

#define BATCH  4
#define SEQ    2048
#define DMODEL 1024
#define DFF    4096
#define MTOT   (BATCH * SEQ)   // 8192
#define KCONV  5
#define PADC   2

using bf16raw = unsigned short;
typedef __attribute__((ext_vector_type(8))) short bf16x8;
typedef __attribute__((ext_vector_type(4))) float f32x4;

__device__ __forceinline__ float bf2f(bf16raw u) {
    return __uint_as_float(((uint32_t)u) << 16);
}
__device__ __forceinline__ bf16raw f2bf(float f) {
    uint32_t u = __float_as_uint(f);
    u = (u + 0x7fffu + ((u >> 16) & 1u)) >> 16;   // RNE
    return (bf16raw)u;
}

// ---------------- prep kernels ----------------

__global__ __launch_bounds__(256)
void cvt_bf16_kernel(const float* __restrict__ in, bf16raw* __restrict__ out, int n4)
{
    const int i = blockIdx.x * 256 + threadIdx.x;
    if (i >= n4) return;
    const float4 v = reinterpret_cast<const float4*>(in)[i];
    ushort4 o;
    o.x = f2bf(v.x); o.y = f2bf(v.y); o.z = f2bf(v.z); o.w = f2bf(v.w);
    reinterpret_cast<ushort4*>(out)[i] = o;
}

// out[C][R] = bf16(in[R][C]); R,C multiples of 32
__global__ __launch_bounds__(256)
void transpose_cvt_kernel(const float* __restrict__ in, bf16raw* __restrict__ out,
                          int R, int C)
{
    __shared__ float tile[32][33];
    const int r0 = blockIdx.y * 32, c0 = blockIdx.x * 32;
    const int tx = threadIdx.x & 31, ty = threadIdx.x >> 5;  // ty 0..7
#pragma unroll
    for (int i = 0; i < 4; ++i)
        tile[ty + i * 8][tx] = in[(size_t)(r0 + ty + i * 8) * C + c0 + tx];
    __syncthreads();
#pragma unroll
    for (int i = 0; i < 4; ++i)
        out[(size_t)(c0 + ty + i * 8) * R + r0 + tx] = f2bf(tile[tx][ty + i * 8]);
}

// conv weights [DFF][1][K] -> [K][DFF] fp32
__global__ __launch_bounds__(256)
void convw_reorder_kernel(const float* __restrict__ wg, const float* __restrict__ wu,
                          float* __restrict__ wgT, float* __restrict__ wuT)
{
    const int i = blockIdx.x * 256 + threadIdx.x;
    if (i >= KCONV * DFF) return;
    const int j = i / DFF, f = i - j * DFF;
    wgT[i] = wg[f * KCONV + j];
    wuT[i] = wu[f * KCONV + j];
}

// -- 256x256 GEMM, BK=32, 4-buf ring (depth 2-3), 4-phase read-ahead (r10 body) --
// r11 change: block mapping = IDENTITY (no XCD swizzle), row-major (bx fastest).
// Evidence: r4-r10 FETCH ~4x compulsory on both GEMMs (down: 277MB ~= 4x h) =>
// zero L2 panel reuse. The old swz assumed round-robin bid->XCD; if dispatch is
// CHUNKED, it scrambles locality (matches observed FETCH). Identity + bx-fast
// makes the nbn panel-sharing blocks consecutive: chunked -> same XCD-L2 (panel
// fetched once); round-robin -> no worse than today. Discriminating probe.
// C[M][N] = A[M][K] @ BT[N][K]^T (+bias); M,N %256==0, K%(32*SPLITK)==0, NT>=4.
// Swizzle (0-conflict proven): 64B rows, phys16B = log ^ ((row>>1)&3).

__device__ __forceinline__ void gll16(const bf16raw* g, const char* lds)
{
    __builtin_amdgcn_global_load_lds(
        (const __attribute__((address_space(1))) void*)g,
        (__attribute__((address_space(3))) void*)lds, 16, 0, 0);
}

template<typename CT, bool BIAS, int SPLITK, bool COLMAJOR>
__global__ __launch_bounds__(512, 2)
void gemmp_kernel(const bf16raw* __restrict__ A, const bf16raw* __restrict__ BT,
                  const float* __restrict__ bias0, const float* __restrict__ bias1,
                  CT* __restrict__ C, int M, int N, int K, int nbm, int nbn)
{
    __shared__ __align__(16) char smem[131072];   // 4 bufs x (A 16K | B 16K)

    const int tid  = threadIdx.x;
    const int lane = tid & 63;
    const int wave = __builtin_amdgcn_readfirstlane(tid >> 6);
    const int wr = wave >> 2;          // 0..1 (M)
    const int wc = wave & 3;           // 0..3 (N)

    // ---- r11: identity mapping (no XCD swizzle) ----
    const int bid = blockIdx.x;
    int sk = 0, rem = bid;
    if constexpr (SPLITK > 1) { sk = rem / (nbm * nbn); rem = rem - sk * (nbm * nbn); }
    int bx, by;
    if constexpr (COLMAJOR) { bx = rem / nbm; by = rem - bx * nbm; }   // by fastest
    else                    { by = rem / nbn; bx = rem - by * nbn; }   // bx fastest
    const int bm = by * 256;
    const int bn = bx * 256;

    const int klen = K / SPLITK;
    const int kbeg = sk * klen;
    const int NT   = klen / 32;
    CT* Cp = C + (size_t)sk * M * N;

    // staging: thread -> row = half*128 + tid>>2, phys 16B chunk = tid&3.
    // LDS dest linear in lane: (l>>2)*64 + (l&3)*16 == 16*l  (gll-safe).
    const int srow  = tid >> 2;               // 0..127
    const int sphys = tid & 3;

    auto stage = [&](int t) {
#pragma unroll
        for (int half = 0; half < 2; ++half) {
            const int row = half * 128 + srow;
            gll16(A + (size_t)(bm + row) * K + kbeg + t * 32
                    + ((sphys ^ ((row >> 1) & 3)) << 3),
                  smem + (size_t)(t & 3) * 32768 + row * 64 + sphys * 16);
        }
#pragma unroll
        for (int half = 0; half < 2; ++half) {
            const int row = half * 128 + srow;
            gll16(BT + (size_t)(bn + row) * K + kbeg + t * 32
                    + ((sphys ^ ((row >> 1) & 3)) << 3),
                  smem + (size_t)(t & 3) * 32768 + 16384 + row * 64 + sphys * 16);
        }
    };

    // fragment reads: row = base + r15; swizzle key depends only on (r15>>1)&3
    const int g4   = lane >> 4;
    const int r15  = lane & 15;
    const int koff = ((g4 ^ ((r15 >> 1) & 3)) << 4);

    auto ldA = [&](int buf, int mf) -> bf16x8 {
        return *(const bf16x8*)(smem + (size_t)buf * 32768
                                + (wr * 128 + mf * 16 + r15) * 64 + koff);
    };
    auto ldB = [&](int buf, int nf) -> bf16x8 {
        return *(const bf16x8*)(smem + (size_t)buf * 32768 + 16384
                                + (wc * 64 + nf * 16 + r15) * 64 + koff);
    };

    f32x4 acc[8][4];
#pragma unroll
    for (int i = 0; i < 8; ++i)
#pragma unroll
        for (int j = 0; j < 4; ++j) acc[i][j] = (f32x4){0.f, 0.f, 0.f, 0.f};

    bf16x8 A0[2], A1[2], Bb0[4], Bb1[4];

#define MFMA_SET(M0, ASET, BSET)                                               \
    __builtin_amdgcn_s_setprio(1);                                             \
    _Pragma("unroll")                                                          \
    for (int i_ = 0; i_ < 2; ++i_)                                             \
        _Pragma("unroll")                                                      \
        for (int nf_ = 0; nf_ < 4; ++nf_)                                      \
            acc[(M0) + i_][nf_] = __builtin_amdgcn_mfma_f32_16x16x32_bf16(     \
                ASET[i_], BSET[nf_], acc[(M0) + i_][nf_], 0, 0, 0);            \
    __builtin_amdgcn_s_setprio(0);

#define TILE_BODY(T, BC, BN)                                                   \
    {                                                                          \
        const int t_   = (T);                                                  \
        const int buf_ = t_ & 3;                                               \
        /* s0: read set1 -> A1; MFMA set0 (A0 x BC) */                         \
        A1[0] = ldA(buf_, 2); A1[1] = ldA(buf_, 3);                            \
        MFMA_SET(0, A0, BC)                                                    \
        /* s1: read set2 -> A0; MFMA set1 (A1 x BC) */                         \
        A0[0] = ldA(buf_, 4); A0[1] = ldA(buf_, 5);                            \
        MFMA_SET(2, A1, BC)                                                    \
        /* s2: read set3 -> A1; MFMA set2 (A0 x BC) */                         \
        A1[0] = ldA(buf_, 6); A1[1] = ldA(buf_, 7);                            \
        MFMA_SET(4, A0, BC)                                                    \
        /* sync: drain tile t+1's 4 loads, keep t+2's in flight */             \
        if (t_ + 2 < NT) asm volatile("s_waitcnt vmcnt(4)" ::: "memory");      \
        else             asm volatile("s_waitcnt vmcnt(0)" ::: "memory");      \
        __builtin_amdgcn_s_barrier();                                          \
        asm volatile("" ::: "memory");                                         \
        if (t_ + 3 < NT) stage(t_ + 3);                                        \
        /* s3: read set0(t+1) -> BN + A0; MFMA set3 (A1 x BC) */               \
        if (t_ + 1 < NT) {                                                     \
            const int nb_ = (t_ + 1) & 3;                                      \
            BN[0] = ldB(nb_, 0); BN[1] = ldB(nb_, 1);                          \
            BN[2] = ldB(nb_, 2); BN[3] = ldB(nb_, 3);                          \
            A0[0] = ldA(nb_, 0); A0[1] = ldA(nb_, 1);                          \
        }                                                                      \
        MFMA_SET(6, A1, BC)                                                    \
        asm volatile("" ::: "memory");                                         \
    }

    // prologue: stage tiles 0..2, wait tile0, read set0(0)
    stage(0);
    if (NT > 1) stage(1);
    if (NT > 2) stage(2);
    if (NT > 2)      asm volatile("s_waitcnt vmcnt(8)" ::: "memory");
    else if (NT > 1) asm volatile("s_waitcnt vmcnt(4)" ::: "memory");
    else             asm volatile("s_waitcnt vmcnt(0)" ::: "memory");
    __builtin_amdgcn_s_barrier();
    asm volatile("" ::: "memory");
    Bb0[0] = ldB(0, 0); Bb0[1] = ldB(0, 1); Bb0[2] = ldB(0, 2); Bb0[3] = ldB(0, 3);
    A0[0]  = ldA(0, 0); A0[1]  = ldA(0, 1);

    for (int tt = 0; tt < NT; tt += 2) {
        TILE_BODY(tt, Bb0, Bb1)
        if (tt + 1 < NT) TILE_BODY(tt + 1, Bb1, Bb0)
    }
#undef TILE_BODY
#undef MFMA_SET

    // ---- epilogue: C/D layout col=lane&15, row=(lane>>4)*4+reg  [m89] ----
    const int er = g4 << 2;
#pragma unroll
    for (int nf = 0; nf < 4; ++nf) {
        const int nn = bn + wc * 64 + nf * 16 + r15;
        float bv = 0.f;
        if constexpr (BIAS) bv = (nn < DFF) ? bias0[nn] : bias1[nn - DFF];
#pragma unroll
        for (int mf = 0; mf < 8; ++mf) {
            const int mrow = bm + wr * 128 + mf * 16 + er;
#pragma unroll
            for (int j = 0; j < 4; ++j) {
                const float v = acc[mf][nf][j] + bv;
                if constexpr (sizeof(CT) == 2)
                    Cp[(size_t)(mrow + j) * N + nn] = f2bf(v);
                else
                    Cp[(size_t)(mrow + j) * N + nn] = v;
            }
        }
    }
}

// ---------------- split-K reduce + bias (fp32 partials -> fp32 out) --------
template<int NS>
__global__ __launch_bounds__(256)
void reduce_bias_kernel(const float* __restrict__ part, const float* __restrict__ bd,
                        float* __restrict__ out)
{
    const int i = blockIdx.x * 256 + threadIdx.x;           // float4 index
    const int d = (i & (DMODEL / 4 - 1)) * 4;
    const float4 bb = *reinterpret_cast<const float4*>(bd + d);
    float4 o; o.x = bb.x; o.y = bb.y; o.z = bb.z; o.w = bb.w;
#pragma unroll
    for (int s = 0; s < NS; ++s) {
        const float4 a = reinterpret_cast<const float4*>(part + (size_t)s * MTOT * DMODEL)[i];
        o.x += a.x; o.y += a.y; o.z += a.z; o.w += a.w;
    }
    reinterpret_cast<float4*>(out)[i] = o;
}

// ---------------- conv + silu + mul (bf16 in/out, src row stride S) --------
__global__ __launch_bounds__(256)
void conv_silu_mul_bf16_kernel(const bf16raw* __restrict__ gp, const bf16raw* __restrict__ up,
                               const float* __restrict__ wgT, const float* __restrict__ cbg,
                               const float* __restrict__ wuT, const float* __restrict__ cbu,
                               bf16raw* __restrict__ h, int S)
{
    const int idx = blockIdx.x * 256 + threadIdx.x;
    const int f   = (idx & (DFF / 8 - 1)) << 3;
    const int row = idx >> 9;
    const int l   = row & (SEQ - 1);
    const int rb  = row - l;                       // batch base row

    float g[8], u[8];
    {
        const float4 a0 = *reinterpret_cast<const float4*>(cbg + f);
        const float4 a1 = *reinterpret_cast<const float4*>(cbg + f + 4);
        const float4 b0 = *reinterpret_cast<const float4*>(cbu + f);
        const float4 b1 = *reinterpret_cast<const float4*>(cbu + f + 4);
        g[0]=a0.x; g[1]=a0.y; g[2]=a0.z; g[3]=a0.w; g[4]=a1.x; g[5]=a1.y; g[6]=a1.z; g[7]=a1.w;
        u[0]=b0.x; u[1]=b0.y; u[2]=b0.z; u[3]=b0.w; u[4]=b1.x; u[5]=b1.y; u[6]=b1.z; u[7]=b1.w;
    }

#pragma unroll
    for (int j = 0; j < KCONV; ++j) {
        const int ls = l + j - PADC;
        if (ls < 0 || ls >= SEQ) continue;          // per-batch zero padding
        const size_t off = (size_t)(rb + ls) * S + f;
        const bf16x8 gv = *reinterpret_cast<const bf16x8*>(gp + off);
        const bf16x8 uv = *reinterpret_cast<const bf16x8*>(up + off);
        const float4 wa0 = *reinterpret_cast<const float4*>(wgT + j * DFF + f);
        const float4 wa1 = *reinterpret_cast<const float4*>(wgT + j * DFF + f + 4);
        const float4 wb0 = *reinterpret_cast<const float4*>(wuT + j * DFF + f);
        const float4 wb1 = *reinterpret_cast<const float4*>(wuT + j * DFF + f + 4);
        const float wg8[8] = {wa0.x, wa0.y, wa0.z, wa0.w, wa1.x, wa1.y, wa1.z, wa1.w};
        const float wu8[8] = {wb0.x, wb0.y, wb0.z, wb0.w, wb1.x, wb1.y, wb1.z, wb1.w};
#pragma unroll
        for (int c = 0; c < 8; ++c) {
            g[c] += bf2f((bf16raw)gv[c]) * wg8[c];
            u[c] += bf2f((bf16raw)uv[c]) * wu8[c];
        }
    }

    bf16x8 hv;
#pragma unroll
    for (int c = 0; c < 8; ++c) {
        const float s = g[c] / (1.f + __expf(-g[c]));
        hv[c] = (short)f2bf(s * u[c]);
    }
    *reinterpret_cast<bf16x8*>(h + (size_t)row * DFF + f) = hv;
}

// ---------------- fp32 fallback kernels (round-2 proven) -------------------

#define BM 128
#define BN 128
#define BK 8

__device__ __forceinline__ void load4f(const float* p, float v[4]) {
    const float4 t = *reinterpret_cast<const float4*>(p);
    v[0] = t.x; v[1] = t.y; v[2] = t.z; v[3] = t.w;
}

__global__ __launch_bounds__(256)
void sgemm_bias_kernel(const float* __restrict__ A, const float* __restrict__ B,
                       const float* __restrict__ bias, float* __restrict__ C,
                       int N, int K)
{
    __shared__ float As[BK][BM];
    __shared__ float Bs[BK][BN];

    const int tid = threadIdx.x;
    const int bm  = blockIdx.y * BM;
    const int bn  = blockIdx.x * BN;
    const int tx  = tid & 15;
    const int ty  = tid >> 4;

    const int arow = tid >> 1;
    const int acol = (tid & 1) * 4;
    const int brow = tid >> 5;
    const int bcol = (tid & 31) * 4;

    const float* Ap = A + (size_t)(bm + arow) * K + acol;
    const float* Bp = B + (size_t)brow * N + bn + bcol;

    float acc[8][8];
#pragma unroll
    for (int i = 0; i < 8; ++i)
#pragma unroll
        for (int j = 0; j < 8; ++j) acc[i][j] = 0.f;

    for (int k0 = 0; k0 < K; k0 += BK) {
        float av[4];
        load4f(Ap + k0, av);
        const float4 bv = *reinterpret_cast<const float4*>(Bp + (size_t)k0 * N);
        __syncthreads();
#pragma unroll
        for (int i = 0; i < 4; ++i) As[acol + i][arow] = av[i];
        *reinterpret_cast<float4*>(&Bs[brow][bcol]) = bv;
        __syncthreads();
#pragma unroll
        for (int kk = 0; kk < BK; ++kk) {
            const float4 a0 = *reinterpret_cast<const float4*>(&As[kk][ty * 4]);
            const float4 a1 = *reinterpret_cast<const float4*>(&As[kk][64 + ty * 4]);
            const float4 b0 = *reinterpret_cast<const float4*>(&Bs[kk][tx * 4]);
            const float4 b1 = *reinterpret_cast<const float4*>(&Bs[kk][64 + tx * 4]);
            const float am[8] = {a0.x, a0.y, a0.z, a0.w, a1.x, a1.y, a1.z, a1.w};
            const float bb[8] = {b0.x, b0.y, b0.z, b0.w, b1.x, b1.y, b1.z, b1.w};
#pragma unroll
            for (int mi = 0; mi < 8; ++mi)
#pragma unroll
                for (int nj = 0; nj < 8; ++nj)
                    acc[mi][nj] += am[mi] * bb[nj];
        }
    }
#pragma unroll
    for (int mi = 0; mi < 8; ++mi) {
        const int m = bm + ((mi < 4) ? (ty * 4 + mi) : (64 + ty * 4 + (mi - 4)));
#pragma unroll
        for (int g = 0; g < 2; ++g) {
            const int n = bn + g * 64 + tx * 4;
            float4 o;
            o.x = acc[mi][g * 4 + 0] + bias[n + 0];
            o.y = acc[mi][g * 4 + 1] + bias[n + 1];
            o.z = acc[mi][g * 4 + 2] + bias[n + 2];
            o.w = acc[mi][g * 4 + 3] + bias[n + 3];
            *reinterpret_cast<float4*>(&C[(size_t)m * N + n]) = o;
        }
    }
}

__global__ __launch_bounds__(256)
void conv_silu_mul_f32_kernel(const float* __restrict__ gp, const float* __restrict__ up,
                              const float* __restrict__ wg, const float* __restrict__ cbg,
                              const float* __restrict__ wu, const float* __restrict__ cbu,
                              float* __restrict__ hout)
{
    const int idx = blockIdx.x * 256 + threadIdx.x;
    const int f   = (idx & (DFF / 4 - 1)) * 4;
    const int l   = idx >> 10;

    float g[4], u[4];
    load4f(cbg + f, g);
    load4f(cbu + f, u);
#pragma unroll
    for (int j = 0; j < KCONV; ++j) {
        const int ls = l + j - PADC;
        if (ls < 0 || ls >= SEQ) continue;
        const size_t off = (size_t)ls * DFF + f;
        float gv[4], uv[4];
        load4f(gp + off, gv);
        load4f(up + off, uv);
#pragma unroll
        for (int c = 0; c < 4; ++c) {
            g[c] += gv[c] * wg[(f + c) * KCONV + j];
            u[c] += uv[c] * wu[(f + c) * KCONV + j];
        }
    }
    float h[4];
#pragma unroll
    for (int c = 0; c < 4; ++c) {
        const float s = g[c] / (1.f + __expf(-g[c]));
        h[c] = s * u[c];
    }
    float4 o; o.x = h[0]; o.y = h[1]; o.z = h[2]; o.w = h[3];
    *reinterpret_cast<float4*>(&hout[(size_t)l * DFF + f]) = o;
}

// ---------------- launch ----------------

extern "C" void kernel_launch(void* const* d_in, const int* in_sizes, int n_in,
                              void* d_out, int out_size, void* d_ws, size_t ws_size,
                              hipStream_t stream)
{
    const float* x   = (const float*)d_in[0];
    const float* Wg  = (const float*)d_in[1];
    const float* bg  = (const float*)d_in[2];
    const float* Wu  = (const float*)d_in[3];
    const float* bu  = (const float*)d_in[4];
    const float* cgw = (const float*)d_in[5];
    const float* cgb = (const float*)d_in[6];
    const float* cuw = (const float*)d_in[7];
    const float* cub = (const float*)d_in[8];
    const float* Wd  = (const float*)d_in[9];
    const float* bd  = (const float*)d_in[10];
    float* out = (float*)d_out;

    const dim3 blk(256);
    auto align256 = [](size_t v) { return (v + 255) & ~(size_t)255; };

    const size_t SZ_XB  = (size_t)MTOT * DMODEL * 2;        // 16 MiB
    const size_t SZ_WGU = (size_t)2 * DFF * DMODEL * 2;     // 16 MiB (Wg^T | Wu^T)
    const size_t SZ_WD  = (size_t)DMODEL * DFF * 2;         //  8 MiB
    const size_t SZ_CW  = (size_t)KCONV * DFF * 4;          // 80 KiB each
    const size_t SZ_H   = (size_t)MTOT * DFF * 2;           // 64 MiB
    const size_t SZ_UP  = (size_t)MTOT * 2 * DFF * 2;       // 128 MiB  [8192][8192] bf16

    size_t cur = 0;
    const size_t oXB  = cur; cur = align256(cur + SZ_XB);
    const size_t oWGU = cur; cur = align256(cur + SZ_WGU);
    const size_t oWD  = cur; cur = align256(cur + SZ_WD);
    const size_t oCWg = cur; cur = align256(cur + SZ_CW);
    const size_t oCWu = cur; cur = align256(cur + SZ_CW);
    const size_t oH   = cur; cur = align256(cur + SZ_H);
    const size_t oUP  = cur; cur = align256(cur + SZ_UP);
    const size_t need = cur;

    if (ws_size >= need) {
        bf16raw* xb   = (bf16raw*)((char*)d_ws + oXB);
        bf16raw* Wgu  = (bf16raw*)((char*)d_ws + oWGU);
        bf16raw* WdT  = (bf16raw*)((char*)d_ws + oWD);
        float*   cwg  = (float*)((char*)d_ws + oCWg);
        float*   cwu  = (float*)((char*)d_ws + oCWu);
        bf16raw* h    = (bf16raw*)((char*)d_ws + oH);
        bf16raw* Cup  = (bf16raw*)((char*)d_ws + oUP);
        float*   part = (float*)((char*)d_ws + oUP);        // overlay (conv consumed Cup)

        cvt_bf16_kernel<<<(MTOT * DMODEL / 4 + 255) / 256, blk, 0, stream>>>(x, xb, MTOT * DMODEL / 4);
        transpose_cvt_kernel<<<dim3(DFF / 32, DMODEL / 32), blk, 0, stream>>>(Wg, Wgu, DMODEL, DFF);
        transpose_cvt_kernel<<<dim3(DFF / 32, DMODEL / 32), blk, 0, stream>>>(Wu, Wgu + (size_t)DFF * DMODEL, DMODEL, DFF);
        transpose_cvt_kernel<<<dim3(DMODEL / 32, DFF / 32), blk, 0, stream>>>(Wd, WdT, DFF, DMODEL);
        convw_reorder_kernel<<<(KCONV * DFF + 255) / 256, blk, 0, stream>>>(cgw, cuw, cwg, cwu);

        // fused up-GEMM: [8192,1024] @ [1024,8192(=Wg|Wu)] -> Cup [8192][8192] bf16
        // identity mapping, bx fastest (x-panel stationary per consecutive 32 blocks)
        {
            const int nbm = MTOT / 256, nbn = (2 * DFF) / 256;   // 32 x 32 -> 1024 wg
            gemmp_kernel<bf16raw, true, 1, false><<<nbm * nbn, dim3(512), 0, stream>>>(
                xb, Wgu, bg, bu, Cup, MTOT, 2 * DFF, DMODEL, nbm, nbn);
        }

        // conv + silu + mul: Cup(gate 0..4095 | up 4096..8191) -> h bf16
        conv_silu_mul_bf16_kernel<<<MTOT * (DFF / 8) / 256, blk, 0, stream>>>(
            Cup, Cup + DFF, cwg, cgb, cwu, cub, h, 2 * DFF);

        // down-GEMM split-K=2, identity mapping, bx fastest (the 4 blocks sharing
        // an h-panel are consecutive -> same XCD-L2 if dispatch is chunked)
        {
            const int nbm = MTOT / 256, nbn = DMODEL / 256;      // 32 x 4, x2 sk
            gemmp_kernel<float, false, 2, false><<<nbm * nbn * 2, dim3(512), 0, stream>>>(
                h, WdT, nullptr, nullptr, part, MTOT, DMODEL, DFF, nbm, nbn);
        }
        reduce_bias_kernel<2><<<MTOT * DMODEL / 4 / 256, blk, 0, stream>>>(part, bd, out);
        return;
    }

    // -------- fp32 per-batch fallback --------
    const size_t CE  = (size_t)SEQ * DFF;
    const size_t P32 = CE * sizeof(float);
    if (ws_size < 3 * P32) return;

    float* gpre = (float*)d_ws;
    float* upre = gpre + CE;
    float* hbuf = upre + CE;
    dim3 gu(DFF / BN, SEQ / BM);
    dim3 gdc(DMODEL / BN, SEQ / BM);
    const int nconv = SEQ * (DFF / 4) / 256;
    for (int b = 0; b < BATCH; ++b) {
        const float* xbp = x + (size_t)b * SEQ * DMODEL;
        float* outb = out + (size_t)b * SEQ * DMODEL;
        sgemm_bias_kernel<<<gu, blk, 0, stream>>>(xbp, Wg, bg, gpre, DFF, DMODEL);
        sgemm_bias_kernel<<<gu, blk, 0, stream>>>(xbp, Wu, bu, upre, DFF, DMODEL);
        conv_silu_mul_f32_kernel<<<nconv, blk, 0, stream>>>(gpre, upre, cgw, cgb, cuw, cub, hbuf);
        sgemm_bias_kernel<<<gdc, blk, 0, stream>>>(hbuf, Wd, bd, outb, DMODEL, DFF);
    }
}